// Round 2
// baseline (661.711 us; speedup 1.0000x reference)
//
#include <hip/hip_runtime.h>

// Digit-wise subtraction-with-borrow scan in probability space.
// B=65536 independent batches, L=64 sequential steps, K=16 digits.
// One thread per batch; memory-bound (~805 MB total traffic).

constexpr int BATCH = 65536;
constexpr int LSTEPS = 64;
constexpr int KD = 16;

__global__ __launch_bounds__(256, 1) void sub_scan_kernel(
    const float* __restrict__ op1,
    const float* __restrict__ op2,
    float* __restrict__ out)
{
    const int b = blockIdx.x * blockDim.x + threadIdx.x;
    const size_t base = (size_t)b * (LSTEPS * KD / 4);   // in float4 units (=256)
    const float4* __restrict__ A = reinterpret_cast<const float4*>(op1) + base;
    const float4* __restrict__ C = reinterpret_cast<const float4*>(op2) + base;
    float4*       __restrict__ O = reinterpret_cast<float4*>(out) + base;

    float bd0 = 1.0f, bd1 = 0.0f;   // borrow distribution [P(no borrow), P(borrow)]

    // Prefetch pair 0 (2 steps = 128B per operand = full cache lines)
    float4 av[8], cv[8];
    #pragma unroll
    for (int i = 0; i < 8; ++i) { av[i] = A[i]; cv[i] = C[i]; }

    for (int p = 0; p < 32; ++p) {
        // Unpack current pair into scalar regs (all constant indices -> VGPRs)
        float ax[32], cx[32];
        #pragma unroll
        for (int i = 0; i < 8; ++i) {
            ax[4*i+0] = av[i].x; ax[4*i+1] = av[i].y; ax[4*i+2] = av[i].z; ax[4*i+3] = av[i].w;
            cx[4*i+0] = cv[i].x; cx[4*i+1] = cv[i].y; cx[4*i+2] = cv[i].z; cx[4*i+3] = cv[i].w;
        }
        // Software prefetch next pair: loads in flight across the compute phase
        if (p < 31) {
            #pragma unroll
            for (int i = 0; i < 8; ++i) { av[i] = A[(p+1)*8 + i]; cv[i] = C[(p+1)*8 + i]; }
        }

        float ox[32];
        #pragma unroll
        for (int s = 0; s < 2; ++s) {
            // r[v] = sum_x a[x] * c[(x - v) & 15]   (cyclic correlation)
            float r[16];
            #pragma unroll
            for (int v = 0; v < KD; ++v) {
                float acc = ax[s*16 + 0] * cx[s*16 + ((0 - v) & 15)];
                #pragma unroll
                for (int x = 1; x < KD; ++x)
                    acc = fmaf(ax[s*16 + x], cx[s*16 + ((x - v) & 15)], acc);
                r[v] = acc;
            }
            // s_gt = sum_x a[x] * (sum_{y>x} c[y]) via suffix sum; tgt ends as sum(c)
            float tgt = 0.0f, s_gt = 0.0f;
            #pragma unroll
            for (int x = KD - 1; x >= 0; --x) {
                s_gt = fmaf(ax[s*16 + x], tgt, s_gt);
                tgt += cx[s*16 + x];
            }
            float sa = 0.0f;
            #pragma unroll
            for (int x = 0; x < KD; ++x) sa += ax[s*16 + x];
            const float sc    = tgt;
            const float total = sa * sc * (bd0 + bd1);
            // s_ge = s_gt + dot(a,c); dot(a,c) == r[0]
            const float s_ge = s_gt + r[0];
            const float p1   = fmaf(bd0, s_gt, bd1 * s_ge);

            // res[v] = bd0*r[v] + bd1*r[(v+1)&15]  (uses OLD borrow dist)
            #pragma unroll
            for (int v = 0; v < KD; ++v)
                ox[s*16 + v] = fmaf(bd0, r[v], bd1 * r[(v + 1) & 15]);

            bd0 = total - p1;
            bd1 = p1;
        }

        #pragma unroll
        for (int i = 0; i < 8; ++i)
            O[p*8 + i] = make_float4(ox[4*i+0], ox[4*i+1], ox[4*i+2], ox[4*i+3]);
    }
}

extern "C" void kernel_launch(void* const* d_in, const int* in_sizes, int n_in,
                              void* d_out, int out_size, void* d_ws, size_t ws_size,
                              hipStream_t stream) {
    const float* op1 = (const float*)d_in[0];
    const float* op2 = (const float*)d_in[1];
    float* out = (float*)d_out;
    dim3 block(256);
    dim3 grid(BATCH / 256);
    hipLaunchKernelGGL(sub_scan_kernel, grid, block, 0, stream, op1, op2, out);
}